// Round 1
// baseline (575.652 us; speedup 1.0000x reference)
//
#include <hip/hip_runtime.h>
#include <math.h>

#define N_ROWS 131072
#define D 512
#define BLOCKS 4096
#define ALPHA 50.0f
#define BETA 0.5f
#define EPS 1e-6f

// numerically stable softplus
__device__ __forceinline__ float softplusf(float x) {
    if (x > 0.0f) return x + log1pf(__expf(-x));
    return log1pf(__expf(x));
}

__global__ __launch_bounds__(256) void binloss_main(
    const float* __restrict__ o1, const float* __restrict__ o2,
    const int* __restrict__ target,
    float* __restrict__ sums /* [pos_sum, neg_sum] */,
    int* __restrict__ cnt /* [num_pos] */) {

    const int lane = threadIdx.x & 63;
    const int wave = threadIdx.x >> 6;           // 0..3
    const int gwave = blockIdx.x * 4 + wave;
    const int nwaves = gridDim.x * 4;

    float posAcc = 0.0f, negAcc = 0.0f;
    int posCnt = 0;

    for (int row = gwave; row < N_ROWS; row += nwaves) {
        const float4* p1 = (const float4*)(o1 + (size_t)row * D);
        const float4* p2 = (const float4*)(o2 + (size_t)row * D);
        // 64 lanes x 2 float4 = 512 floats, fully coalesced 16B/lane
        float4 a0 = p1[lane];
        float4 a1 = p1[lane + 64];
        float4 b0 = p2[lane];
        float4 b1 = p2[lane + 64];

        float dot = a0.x * b0.x + a0.y * b0.y + a0.z * b0.z + a0.w * b0.w
                  + a1.x * b1.x + a1.y * b1.y + a1.z * b1.z + a1.w * b1.w;
        float s1  = a0.x * a0.x + a0.y * a0.y + a0.z * a0.z + a0.w * a0.w
                  + a1.x * a1.x + a1.y * a1.y + a1.z * a1.z + a1.w * a1.w;
        float s2  = b0.x * b0.x + b0.y * b0.y + b0.z * b0.z + b0.w * b0.w
                  + b1.x * b1.x + b1.y * b1.y + b1.z * b1.z + b1.w * b1.w;

        // 64-lane butterfly reduction of 3 values
        #pragma unroll
        for (int off = 32; off > 0; off >>= 1) {
            dot += __shfl_xor(dot, off);
            s1  += __shfl_xor(s1, off);
            s2  += __shfl_xor(s2, off);
        }

        if (lane == 0) {
            float denom = fmaxf(sqrtf(s1) * sqrtf(s2), EPS);
            float d = dot / denom;
            int t = target[row];
            if (t == 1) {
                posAcc += (2.0f / BETA) * softplusf(-BETA * (d - 0.5f));
                posCnt++;
            } else {
                negAcc += (2.0f / ALPHA) * softplusf(ALPHA * (d - 2.0f));
            }
        }
    }

    // block reduction: lane 0 of each of 4 waves -> LDS -> one atomic set per block
    __shared__ float sPos[4], sNeg[4];
    __shared__ int sCnt[4];
    if (lane == 0) {
        sPos[wave] = posAcc;
        sNeg[wave] = negAcc;
        sCnt[wave] = posCnt;
    }
    __syncthreads();
    if (threadIdx.x == 0) {
        float p = sPos[0] + sPos[1] + sPos[2] + sPos[3];
        float n = sNeg[0] + sNeg[1] + sNeg[2] + sNeg[3];
        int c = sCnt[0] + sCnt[1] + sCnt[2] + sCnt[3];
        atomicAdd(&sums[0], p);
        atomicAdd(&sums[1], n);
        atomicAdd(&cnt[0], c);
    }
}

__global__ void binloss_final(const float* __restrict__ sums,
                              const int* __restrict__ cnt,
                              float* __restrict__ out) {
    int np = cnt[0];
    int nn = N_ROWS - np;
    float pos_loss = sums[0] / (float)(np > 1 ? np : 1);
    float neg_loss = sums[1] / (float)(nn > 1 ? nn : 1);
    out[0] = pos_loss + neg_loss;
}

extern "C" void kernel_launch(void* const* d_in, const int* in_sizes, int n_in,
                              void* d_out, int out_size, void* d_ws, size_t ws_size,
                              hipStream_t stream) {
    const float* o1 = (const float*)d_in[0];
    const float* o2 = (const float*)d_in[1];
    const int* tgt = (const int*)d_in[2];
    float* out = (float*)d_out;
    float* sums = (float*)d_ws;
    int* cnt = (int*)((char*)d_ws + 2 * sizeof(float));

    // zero the 3 accumulators (ws is re-poisoned to 0xAA before every launch)
    hipMemsetAsync(d_ws, 0, 16, stream);

    binloss_main<<<BLOCKS, 256, 0, stream>>>(o1, o2, tgt, sums, cnt);
    binloss_final<<<1, 1, 0, stream>>>(sums, cnt, out);
}